// Round 4
// baseline (239.069 us; speedup 1.0000x reference)
//
#include <hip/hip_runtime.h>

#define B_   2
#define NC_  256
#define CN_  256
#define K_   16
#define DN_  64
#define G_   8
#define HM_  128
#define F3_  192

typedef unsigned short u16;
typedef short v8s __attribute__((ext_vector_type(8)));
typedef float v4f __attribute__((ext_vector_type(4)));

// LDS layout (bytes), 2 blocks/CU (<= 80 KB):
//   R0  @ 0     : 36864  hbf [256][72] bf16 (staged h, gather input + h A-frags)
//                        ... after barrier #2 aliased as mh/sh [128][136] bf16
//   am  @ 36864 : 18432  [128][72] bf16 (agg, then msg)
//   ctxl@ 55296 : 128    [64] bf16
//   hsum@ 55424 : 4096   [16][64] f32 partial col-sums of h_new
//   msum@ 59520 : 4096   [16][64] f32 partial col-sums of msg
#define SMEM_BYTES 63616

// d_ws layout: bf16 weight copies then pooled partials
//   mw1b @ u16[0] (196608)  mw2b @ u16[196608] (65536)
//   sw1b @ u16[262144] (196608)  sw2b @ u16[458752] (65536)
//   partial f32 @ byte 1048576 : [1024][128]

__device__ __forceinline__ u16 f2b(float f) {
    unsigned v; __builtin_memcpy(&v, &f, 4);
    v = v + 0x7fffu + ((v >> 16) & 1u);   // RNE
    return (u16)(v >> 16);
}
__device__ __forceinline__ v8s cvt8(const float* p) {
    float4 a = *(const float4*)p, b = *(const float4*)(p + 4);
    v8s r;
    r[0] = (short)f2b(a.x); r[1] = (short)f2b(a.y); r[2] = (short)f2b(a.z); r[3] = (short)f2b(a.w);
    r[4] = (short)f2b(b.x); r[5] = (short)f2b(b.y); r[6] = (short)f2b(b.z); r[7] = (short)f2b(b.w);
    return r;
}
__device__ __forceinline__ float gelu_t(float x) {
    // jax.nn.gelu approximate=True: x*sigmoid(2*k0*x*(1+k1*x^2))
    float u = x * x;
    float t = 1.5957691216057308f * x * __builtin_fmaf(0.044715f, u, 1.0f);
    float e = __expf(-t);
    return x * __builtin_amdgcn_rcpf(1.0f + e);
}

__global__ __launch_bounds__(256) void cvt_w(
    const float* __restrict__ mw1, const float* __restrict__ mw2,
    const float* __restrict__ sw1, const float* __restrict__ sw2,
    u16* __restrict__ dst)
{
    int e = (blockIdx.x * 256 + threadIdx.x) * 4;   // 131072 threads * 4 = 524288
    const float* s; int off;
    if      (e < 196608) { s = mw1; off = e; }
    else if (e < 262144) { s = mw2; off = e - 196608; }
    else if (e < 458752) { s = sw1; off = e - 262144; }
    else                 { s = sw2; off = e - 458752; }
    float4 v = *(const float4*)(s + off);
    ushort4 o4;
    o4.x = f2b(v.x); o4.y = f2b(v.y); o4.z = f2b(v.z); o4.w = f2b(v.w);
    *(ushort4*)(dst + e) = o4;
}

__global__ __launch_bounds__(256, 2) void mg_main(
    const float* __restrict__ h,    const float* __restrict__ wconn,
    const float* __restrict__ ctx,  const float* __restrict__ nid,
    const u16* __restrict__ mw1b,   const float* __restrict__ mb1,
    const u16* __restrict__ mw2b,   const float* __restrict__ mb2,
    const u16* __restrict__ sw1b,   const float* __restrict__ sb1,
    const u16* __restrict__ sw2b,   const float* __restrict__ sb2,
    const int* __restrict__ conn,   const int* __restrict__ c2g,
    float* __restrict__ outf,       float* __restrict__ partial)
{
    const int bx   = blockIdx.x;        // 0..1023
    const int bnc  = bx & 511;          // cell-batch index; pair (c, c+512) -> same XCD
    const int half = bx >> 9;           // 0/1: which 128-row half of the cell
    const int r0   = half * 128;
    const int n    = bnc & 255;
    const int tid  = threadIdx.x;
    const int wave = tid >> 6;          // 0..3
    const int lane = tid & 63;
    const int q    = lane >> 4;
    const int ln   = lane & 15;
    const int g    = c2g[n];

    extern __shared__ char smem[];
    u16*   hbf  = (u16*)(smem);                 // [256][72] bf16 (phase0..gather)
    u16*   mh   = (u16*)(smem);                 // [128][136] bf16 (aliases hbf, post-barrier2)
    u16*   am   = (u16*)(smem + 36864);         // [128][72] bf16
    u16*   ctxl = (u16*)(smem + 55296);
    float* hsum = (float*)(smem + 55424);       // [16][64]
    float* msum = (float*)(smem + 59520);       // [16][64]

    const size_t hbase = (size_t)bnc * (CN_ * DN_);
    const size_t nbase = (size_t)n   * (CN_ * DN_);
    float* oH = outf + (size_t)bnc * 16384;
    float* oM = outf + (size_t)8388608 + (size_t)bnc * 16384;

    // ---------------- phase 0: stage full-cell h as bf16 + ctx ---------------
    if (tid < 64) ctxl[tid] = f2b(ctx[(size_t)bnc * DN_ + tid]);
    {
        const float* hrow = h + hbase + (size_t)tid * DN_;   // tid = cell row 0..255
        u16* drow = hbf + tid * 72;
#pragma unroll
        for (int i = 0; i < 8; ++i)
            *(v8s*)(drow + i * 8) = cvt8(hrow + i * 8);
    }
    __syncthreads();   // barrier #1: hbf ready

    const int cbase = wave * 32;   // local row base; all MLP rows wave-private

    // ---------------- gather (VALU): agg[c][d] = sum_k w*h[conn] -------------
    {
        const int kl = lane & 15;
        const int* cp       = conn + n * 4096 + (size_t)(r0 + cbase) * 16;
        const unsigned* wp  = (const unsigned*)(wconn + (size_t)bnc * 4096 + (size_t)(r0 + cbase) * 16);
        int ivv      = cp[kl];
        unsigned wvv = wp[kl];
        for (int c = 0; c < 32; ++c) {
            int ivn = 0; unsigned wvn = 0u;
            if (c < 31) { ivn = cp[(c + 1) * 16 + kl]; wvn = wp[(c + 1) * 16 + kl]; }
            float acc = 0.0f;
#pragma unroll
            for (int k = 0; k < 16; ++k) {
                int iv = __builtin_amdgcn_readlane(ivv, k);
                int wu = __builtin_amdgcn_readlane((int)wvv, k);
                unsigned hu = (unsigned)hbf[iv * 72 + lane] << 16;
                acc = __builtin_fmaf(__uint_as_float((unsigned)wu), __uint_as_float(hu), acc);
            }
            am[(cbase + c) * 72 + lane] = f2b(acc);
            ivv = ivn; wvv = wvn;
        }
    }

    // Preload wave-private A-fragments from hbf/am BEFORE hbf is reused as mh.
    v8s hfr[2][2], gfr[2][2], nfr[2][2];
#pragma unroll
    for (int mi = 0; mi < 2; ++mi) {
        int c = cbase + mi * 16 + ln;           // local row
        hfr[mi][0] = *(const v8s*)(hbf + (r0 + c) * 72 +  0 + q * 8);
        hfr[mi][1] = *(const v8s*)(hbf + (r0 + c) * 72 + 32 + q * 8);
        gfr[mi][0] = *(const v8s*)(am  + c * 72 +  0 + q * 8);
        gfr[mi][1] = *(const v8s*)(am  + c * 72 + 32 + q * 8);
        nfr[mi][0] = cvt8(nid + nbase + (size_t)(r0 + c) * 64 +  0 + q * 8);
        nfr[mi][1] = cvt8(nid + nbase + (size_t)(r0 + c) * 64 + 32 + q * 8);
    }
    __syncthreads();   // barrier #2: hbf dead -> mh region live

    // ---------------- m1: mh = gelu([h|agg|nid] @ mw1^T + mb1) ---------------
    {
        v8s afr[6] = {hfr[0][0], hfr[0][1], gfr[0][0], gfr[0][1], nfr[0][0], nfr[0][1]};
        v8s afr1[6] = {hfr[1][0], hfr[1][1], gfr[1][0], gfr[1][1], nfr[1][0], nfr[1][1]};
        float b1v[8];
#pragma unroll
        for (int nt = 0; nt < 8; ++nt) b1v[nt] = mb1[g * HM_ + nt * 16 + ln];
        const u16* w1g = mw1b + (size_t)g * HM_ * F3_;
#pragma unroll
        for (int nt = 0; nt < 8; ++nt) {
            v4f acc0 = {0,0,0,0}, acc1 = {0,0,0,0};
#pragma unroll
            for (int ks = 0; ks < 6; ++ks) {
                v8s bf = *(const v8s*)(w1g + (nt * 16 + ln) * F3_ + ks * 32 + q * 8);
                acc0 = __builtin_amdgcn_mfma_f32_16x16x32_bf16(afr[ks],  bf, acc0, 0, 0, 0);
                acc1 = __builtin_amdgcn_mfma_f32_16x16x32_bf16(afr1[ks], bf, acc1, 0, 0, 0);
            }
            int c0 = cbase + q * 4, c1 = cbase + 16 + q * 4;
#pragma unroll
            for (int r = 0; r < 4; ++r) {
                mh[(c0 + r) * 136 + nt * 16 + ln] = f2b(gelu_t(acc0[r] + b1v[nt]));
                mh[(c1 + r) * 136 + nt * 16 + ln] = f2b(gelu_t(acc1[r] + b1v[nt]));
            }
        }
    }

    // ---------------- m2: msg = mh @ mw2^T + mb2 -----------------------------
    {
        v8s afr[2][4];
#pragma unroll
        for (int mi = 0; mi < 2; ++mi) {
            int c = cbase + mi * 16 + ln;
#pragma unroll
            for (int ks = 0; ks < 4; ++ks)
                afr[mi][ks] = *(const v8s*)(mh + c * 136 + ks * 32 + q * 8);
        }
        const u16* w2g = mw2b + (size_t)g * DN_ * HM_;
        float mpart[4];
#pragma unroll
        for (int nt = 0; nt < 4; ++nt) {
            float bb = mb2[g * DN_ + nt * 16 + ln];
            v4f acc[2] = {{0,0,0,0},{0,0,0,0}};
#pragma unroll
            for (int ks = 0; ks < 4; ++ks) {
                v8s bf = *(const v8s*)(w2g + (nt * 16 + ln) * HM_ + ks * 32 + q * 8);
#pragma unroll
                for (int mi = 0; mi < 2; ++mi)
                    acc[mi] = __builtin_amdgcn_mfma_f32_16x16x32_bf16(afr[mi][ks], bf, acc[mi], 0, 0, 0);
            }
            float ms = 0.0f;
            int d = nt * 16 + ln;
#pragma unroll
            for (int mi = 0; mi < 2; ++mi) {
                int c = cbase + mi * 16 + q * 4;
#pragma unroll
                for (int r = 0; r < 4; ++r) {
                    float mv = acc[mi][r] + bb;
                    am[(c + r) * 72 + d] = f2b(mv);                    // msg overwrites agg
                    oM[(size_t)(r0 + c + r) * 64 + d] = mv;
                    ms += mv;
                }
            }
            mpart[nt] = ms;
        }
#pragma unroll
        for (int nt = 0; nt < 4; ++nt)
            msum[(wave * 4 + q) * 64 + nt * 16 + ln] = mpart[nt];
    }

    // ---------------- s1: sh = gelu([h|msg|ctx] @ sw1^T + sb1) ---------------
    {
        v8s cfr0 = *(const v8s*)(ctxl +  0 + q * 8);
        v8s cfr1 = *(const v8s*)(ctxl + 32 + q * 8);
        v8s afr[2][4];
#pragma unroll
        for (int mi = 0; mi < 2; ++mi) {
            int c = cbase + mi * 16 + ln;
            afr[mi][0] = hfr[mi][0];
            afr[mi][1] = hfr[mi][1];
            afr[mi][2] = *(const v8s*)(am + c * 72 +  0 + q * 8);
            afr[mi][3] = *(const v8s*)(am + c * 72 + 32 + q * 8);
        }
        float b1v[8];
#pragma unroll
        for (int nt = 0; nt < 8; ++nt) b1v[nt] = sb1[g * HM_ + nt * 16 + ln];
        const u16* w1g = sw1b + (size_t)g * HM_ * F3_;
#pragma unroll
        for (int nt = 0; nt < 8; ++nt) {
            v4f acc[2] = {{0,0,0,0},{0,0,0,0}};
#pragma unroll
            for (int ks = 0; ks < 4; ++ks) {
                v8s bf = *(const v8s*)(w1g + (nt * 16 + ln) * F3_ + ks * 32 + q * 8);
#pragma unroll
                for (int mi = 0; mi < 2; ++mi)
                    acc[mi] = __builtin_amdgcn_mfma_f32_16x16x32_bf16(afr[mi][ks], bf, acc[mi], 0, 0, 0);
            }
#pragma unroll
            for (int ks = 4; ks < 6; ++ks) {
                v8s bf = *(const v8s*)(w1g + (nt * 16 + ln) * F3_ + ks * 32 + q * 8);
                v8s aa = (ks == 4) ? cfr0 : cfr1;   // ctx broadcast across rows
#pragma unroll
                for (int mi = 0; mi < 2; ++mi)
                    acc[mi] = __builtin_amdgcn_mfma_f32_16x16x32_bf16(aa, bf, acc[mi], 0, 0, 0);
            }
#pragma unroll
            for (int mi = 0; mi < 2; ++mi) {
                int c = cbase + mi * 16 + q * 4;
#pragma unroll
                for (int r = 0; r < 4; ++r)
                    mh[(c + r) * 136 + nt * 16 + ln] = f2b(gelu_t(acc[mi][r] + b1v[nt]));
            }
        }
    }

    // ---------------- s2: h_new = h(f32) + sh @ sw2^T + sb2 ------------------
    {
        v8s afr[2][4];
#pragma unroll
        for (int mi = 0; mi < 2; ++mi) {
            int c = cbase + mi * 16 + ln;
#pragma unroll
            for (int ks = 0; ks < 4; ++ks)
                afr[mi][ks] = *(const v8s*)(mh + c * 136 + ks * 32 + q * 8);
        }
        const u16* w2g = sw2b + (size_t)g * DN_ * HM_;
        float hpart[4];
#pragma unroll
        for (int nt = 0; nt < 4; ++nt) {
            float bb = sb2[g * DN_ + nt * 16 + ln];
            v4f acc[2] = {{0,0,0,0},{0,0,0,0}};
#pragma unroll
            for (int ks = 0; ks < 4; ++ks) {
                v8s bf = *(const v8s*)(w2g + (nt * 16 + ln) * HM_ + ks * 32 + q * 8);
#pragma unroll
                for (int mi = 0; mi < 2; ++mi)
                    acc[mi] = __builtin_amdgcn_mfma_f32_16x16x32_bf16(afr[mi][ks], bf, acc[mi], 0, 0, 0);
            }
            float hs = 0.0f;
            int d = nt * 16 + ln;
#pragma unroll
            for (int mi = 0; mi < 2; ++mi) {
                int c = cbase + mi * 16 + q * 4;
#pragma unroll
                for (int r = 0; r < 4; ++r) {
                    float hv = h[hbase + (size_t)(r0 + c + r) * 64 + d];   // f32 residual
                    float hn = hv + acc[mi][r] + bb;
                    oH[(size_t)(r0 + c + r) * 64 + d] = hn;
                    hs += hn;
                }
            }
            hpart[nt] = hs;
        }
#pragma unroll
        for (int nt = 0; nt < 4; ++nt)
            hsum[(wave * 4 + q) * 64 + nt * 16 + ln] = hpart[nt];
    }
    __syncthreads();   // barrier #3

    // ---------------- pooled partial (this half's 128 rows) ------------------
    if (tid < 128) {
        int col = tid & 63;
        const float* src = (tid < 64) ? hsum : msum;
        float s = 0.0f;
#pragma unroll
        for (int i = 0; i < 16; ++i) s += src[i * 64 + col];
        partial[(size_t)(bnc * 2 + half) * 128 + (tid < 64 ? col : 64 + col)] = s * (1.0f / 256.0f);
    }
}

// ---------------- modulation MLP: mod = gelu(p@w1+b1)@w2+b2 ------------------
__global__ __launch_bounds__(256) void mg_mod(
    const float* __restrict__ w1, const float* __restrict__ b1,
    const float* __restrict__ w2, const float* __restrict__ b2,
    const float* __restrict__ partial, float* __restrict__ outf)
{
    __shared__ float pool[128];
    __shared__ float ph4[4][64];
    const int bnc = blockIdx.x, n = bnc & 255, t = threadIdx.x;
    if (t < 128)
        pool[t] = partial[(size_t)(bnc * 2) * 128 + t] + partial[(size_t)(bnc * 2 + 1) * 128 + t];
    __syncthreads();
    {
        const int col = t & 63, fh = t >> 6;     // 4-way split over f
        const float* w1p = w1 + ((size_t)n * 128 + fh * 32) * 64 + col;
        float acc = 0.0f;
#pragma unroll
        for (int i = 0; i < 32; ++i)
            acc = __builtin_fmaf(pool[fh * 32 + i], w1p[(size_t)i * 64], acc);
        ph4[fh][col] = acc;
    }
    __syncthreads();
    if (t < 64) {
        float a  = ph4[0][t] + ph4[1][t] + ph4[2][t] + ph4[3][t] + b1[n * 64 + t];
        float ph = gelu_t(a);
        float part5[5];
#pragma unroll
        for (int o = 0; o < 5; ++o) part5[o] = ph * w2[((size_t)n * 64 + t) * 5 + o];
#pragma unroll
        for (int off = 32; off > 0; off >>= 1)
#pragma unroll
            for (int o = 0; o < 5; ++o) part5[o] += __shfl_down(part5[o], off);
        if (t == 0) {
#pragma unroll
            for (int o = 0; o < 5; ++o)
                outf[(size_t)16777216 + bnc * 5 + o] = part5[o] + b2[n * 5 + o];
        }
    }
}

extern "C" void kernel_launch(void* const* d_in, const int* in_sizes, int n_in,
                              void* d_out, int out_size, void* d_ws, size_t ws_size,
                              hipStream_t stream) {
    const float* h     = (const float*)d_in[0];
    const float* wconn = (const float*)d_in[1];
    const float* ctx   = (const float*)d_in[2];
    const float* nid   = (const float*)d_in[3];
    const float* mw1   = (const float*)d_in[4];
    const float* mb1   = (const float*)d_in[5];
    const float* mw2   = (const float*)d_in[6];
    const float* mb2   = (const float*)d_in[7];
    const float* sw1   = (const float*)d_in[8];
    const float* sb1   = (const float*)d_in[9];
    const float* sw2   = (const float*)d_in[10];
    const float* sb2   = (const float*)d_in[11];
    const float* dw1   = (const float*)d_in[12];
    const float* db1   = (const float*)d_in[13];
    const float* dw2   = (const float*)d_in[14];
    const float* db2   = (const float*)d_in[15];
    const int* conn    = (const int*)d_in[16];
    const int* c2g     = (const int*)d_in[17];
    float* outf   = (float*)d_out;
    u16*   wb     = (u16*)d_ws;                         // bf16 weight copies
    float* partial = (float*)((char*)d_ws + 1048576);   // [1024][128] pooled partials

    hipFuncSetAttribute(reinterpret_cast<const void*>(&mg_main),
                        hipFuncAttributeMaxDynamicSharedMemorySize, SMEM_BYTES);

    cvt_w<<<512, 256, 0, stream>>>(mw1, mw2, sw1, sw2, wb);
    mg_main<<<1024, 256, SMEM_BYTES, stream>>>(h, wconn, ctx, nid,
                                               wb,           mb1,
                                               wb + 196608,  mb2,
                                               wb + 262144,  sb1,
                                               wb + 458752,  sb2,
                                               conn, c2g, outf, partial);
    mg_mod<<<512, 256, 0, stream>>>(dw1, db1, dw2, db2, partial, outf);
}